// Round 16
// baseline (15.134 us; speedup 1.0000x reference)
//
#include <hip/hip_runtime.h>
#include <hip/hip_bf16.h>

// RDF with minimum-image PBC + Gaussian smearing, N=2048 atoms, 100 bins.
//
// Round-16: r15 with ONE fix — the publish atomicExch is RETURNING.
// r15 passed at absmax 0.1484 (19x the r13 floor, 1% under threshold):
// latent visibility race. Non-returning exch (result unused -> compiler
// emits the no-sc0 form) completes vmcnt on REQUEST ACCEPT, not on
// performance at the coherence point (IF); the relaxed ticket RMW
// (different address) can overtake it in the fabric -> winner reads a row
// that hasn't landed. Consuming the old value forces the returning form
// (sc0): vmcnt waits for the IF round-trip, so after __syncthreads all
// 100 swaps are PERFORMED at IF before thread 0's ticket RMW issues.
// This is why r9 (all-returning-RMW traffic) was always correct and
// r10-r13 needed the ACQ_REL ticket (release writeback = the 13us tax).
//
// Handoff recipe (rest = r15):
//  - publish: returning atomicExch into per-block-unique slots
//    partials[bid][0..99] (stride-112); fully overwritten every call ->
//    no zeroing, no memset node.
//  - tickets: two-level (16 subs x 16 arrivals, 256B apart + 16-arrival
//    master), ALL RELAXED RMWs (execute at IF); modulo trick (16 | 2^32,
//    exact increment counts per call) -> correct from any poison value,
//    never reset.
//  - winner: ONE acquire RMW (single L1/L2 invalidate) + readback via
//    SYSTEM-scope relaxed loads (bypass L1&L2, read at IF), fixed-order
//    reduce -> deterministic.
//
// Compute structure (= r13): 256 blocks x 1024 threads; block owns 8 rows
// of the cyclic upper-triangle enumeration (j=(i+1+t) mod N; one predicate
// dedups the d==N/2 diagonal; x2 pair weight cancels in count
// normalization). i wave-uniform -> scalar i-loads; j-loads coalesced,
// L1-resident (xyz=24KB). ONE u32 LDS atomic per pair into a FINE distance
// histogram (17 sub-bins/bin, 4 private copies; integer counts -> exact,
// order-independent). Epilogue merges copies + convolves with a 103-tap
// Gaussian (stride 17 coprime with 32 banks -> conflict-free). Pairs with
// dist < 8 bin-units (~250 device-wide) take an exact f32 direct-smear
// path into bins 0..11 (tiny shell volumes amplify quantization error
// there). d_out = [count(100) | bins(101) | rdf(100)].

#define N_ATOMS 2048
#define HALF    1024
#define NBINS   100
#define S_FINE  17          // fine sub-bins per coarse bin (coprime with 32)
#define FBINS   1744        // > 102.5 * 17 = 1742.5
#define NCOPY   4           // private fine-histogram copies
#define TAPS    103         // 2*3*17 + 1  (window +-3 bin widths)
#define NDIR    12          // exact direct-path coarse bins 0..11
#define TLOW    8.0f        // bin-units: below this, take the exact path
#define NBLOCKS 256         // power of 2: modulo tickets need divisors of 2^32
#define NTHREADS 1024
#define ROWS_PB 8           // N_ATOMS / NBLOCKS
#define PADB    112         // padded row stride for publish slots
#define NSUB    16          // sub-tickets; NBLOCKS/NSUB = 16 arrivals each
#define TSTRIDE 64          // words between ticket slots (256B apart)

__global__ __launch_bounds__(1024) void rdf_fused(
    const float* __restrict__ xyz,
    const float* __restrict__ cell,
    const float* __restrict__ offsets,
    const float* __restrict__ bins,
    float* __restrict__ out,
    float* __restrict__ partials,   // [NBLOCKS][PADB], exch-overwritten
    unsigned* __restrict__ tickets) // NSUB subs + 1 master, never reset
{
    __shared__ unsigned fine[NCOPY][FBINS];  // private fine histograms (u32)
    __shared__ float wtab[TAPS];             // Gaussian taps
    __shared__ float conv[NBINS][8];         // conv partials / tail reduce
    __shared__ float cd[16];                 // exact direct-path coarse bins
    __shared__ float ssum[2];
    __shared__ unsigned stick;

    const int tid = threadIdx.x;
    const int bid = blockIdx.x;

    for (int a = tid; a < NCOPY * FBINS; a += NTHREADS)
        (&fine[0][0])[a] = 0u;
    if (tid < 16)   cd[tid] = 0.0f;
    if (tid < TAPS) {
        const float u = ((float)tid - 50.5f) * (1.0f / (float)S_FINE);
        wtab[tid] = __expf(-0.5f * u * u);
    }
    __syncthreads();

    const float cx = cell[0], cy = cell[1], cz = cell[2];
    const float hcx = 0.5f * cx, hcy = 0.5f * cy, hcz = 0.5f * cz;

    const float width = offsets[1] - offsets[0];   // 7.5/99
    const float invw  = 1.0f / width;
    // beyond 102.5 bin-units no bin k<=99 lies within the +-3w window
    const float cutd   = 102.5f * width;           // 7.765 < CUTOFF_B = 8.0
    const float cut2   = cutd * cutd;

    unsigned* const myfine = fine[tid >> 8];       // 4 waves per copy

    // ---- main loop: 8 rows per block, one 1024-wide j-sweep per row ----
    const int row0 = bid << 3;
    #pragma unroll
    for (int r = 0; r < ROWS_PB; ++r) {
        const int i = row0 + r;                    // wave-uniform
        const float xi = xyz[3 * i + 0];           // scalar loads
        const float yi = xyz[3 * i + 1];
        const float zi = xyz[3 * i + 2];
        if (tid == HALF - 1 && i >= HALF) continue; // dedup N/2 diagonal
        const int j = (i + 1 + tid) & (N_ATOMS - 1);

        float dx = xyz[3 * j + 0] - xi;            // coalesced, L1-resident
        float dy = xyz[3 * j + 1] - yi;
        float dz = xyz[3 * j + 2] - zi;
        // minimum-image wrap (matches reference shift semantics)
        dx += (dx >= hcx) ? -cx : ((dx < -hcx) ? cx : 0.0f);
        dy += (dy >= hcy) ? -cy : ((dy < -hcy) ? cy : 0.0f);
        dz += (dz >= hcz) ? -cz : ((dz < -hcz) ? cz : 0.0f);

        const float dsq = dx * dx + dy * dy + dz * dz;
        if (dsq < cut2 && dsq != 0.0f) {
            const float tu = sqrtf(dsq) * invw;    // dist in bin units
            if (tu >= TLOW) {
                // ONE native u32 LDS atomic/pair; lanes scatter over 1744
                atomicAdd(&myfine[(int)(tu * (float)S_FINE)], 1u);
            } else {
                // exact f32 path for low bins (~250 pairs device-wide)
                int khi = (int)tu + 4; if (khi > NDIR - 1) khi = NDIR - 1;
                for (int k = 0; k <= khi; ++k) {
                    const float e = tu - (float)k;
                    atomicAdd(&cd[k], __expf(-0.5f * e * e));
                }
            }
        }
    }

    __syncthreads();

    // merge the 4 copies into copy 0 (stride-1, conflict-free, int adds)
    for (int a = tid; a < FBINS; a += NTHREADS)
        fine[0][a] += fine[1][a] + fine[2][a] + fine[3][a];
    __syncthreads();

    // coarse[k] = sum_d wtab[d+51] * fine[17k+d], d in [-51,51]
    // 400 threads: k = t>>2, chunk c = t&3 (26/26/26/25 taps); stride-17
    // fine reads are bank-conflict free (gcd(17,32)=1)
    if (tid < 400) {
        const int k = tid >> 2;
        const int c = tid & 3;
        const int m0 = c * 26;
        const int mcnt = (c == 3) ? 25 : 26;
        float s = 0.0f;
        for (int mm = 0; mm < mcnt; ++mm) {
            const int m = m0 + mm;
            const int f = S_FINE * k + m - 51;     // max 17*99+51 = 1734
            if (f >= 0) s += wtab[m] * (float)fine[0][f];  // exact: < 2^24
        }
        conv[k][c] = s;
    }
    __syncthreads();

    // ---- publish: RETURNING atomicExch into per-block-unique slots.
    // Consuming the old value forces the sc0 (returning) form: vmcnt
    // waits for the IF round-trip, so the swap is PERFORMED at the
    // coherence point before the barrier releases thread 0.
    if (tid < NBINS) {
        float raw = conv[tid][0] + conv[tid][1] + conv[tid][2] + conv[tid][3];
        if (tid < NDIR) raw += cd[tid];
        float old = atomicExch(&partials[bid * PADB + tid], raw);
        asm volatile("" :: "v"(old));   // keep the return value live
    }

    // barrier drains vmcnt: all 100 swaps performed at IF before thread 0
    __syncthreads();
    if (tid == 0) {
        unsigned last = 0u;
        const unsigned so = __hip_atomic_fetch_add(
            &tickets[(bid & (NSUB - 1)) * TSTRIDE], 1u,
            __ATOMIC_RELAXED, __HIP_MEMORY_SCOPE_AGENT);
        if ((so & (NBLOCKS / NSUB - 1)) == (NBLOCKS / NSUB - 1)) {
            // sub-group's last arrival; its RMW completed before this one
            const unsigned mo = __hip_atomic_fetch_add(
                &tickets[NSUB * TSTRIDE], 1u,
                __ATOMIC_RELAXED, __HIP_MEMORY_SCOPE_AGENT);
            last = ((mo & (NSUB - 1)) == (NSUB - 1)) ? 1u : 0u;
        }
        if (last) {
            // ONE acquire (single cache invalidate) for the whole handoff
            __hip_atomic_fetch_add(&tickets[NSUB * TSTRIDE], 0u,
                                   __ATOMIC_ACQUIRE, __HIP_MEMORY_SCOPE_AGENT);
        }
        stick = last;
    }
    __syncthreads();
    if (!stick) return;

    // ---- winner: readback via SYSTEM-scope relaxed loads (bypass L1&L2,
    // read at IF where the swaps landed). thread t: bin b = t&127, chunk
    // c = t>>7; sums 32 blocks each, fixed order -> deterministic.
    {
        const int b = tid & 127;
        const int c = tid >> 7;
        if (b < NBINS) {
            float s = 0.0f;
            #pragma unroll 8
            for (int q = 0; q < NBLOCKS / 8; ++q) {
                const int blk = c * (NBLOCKS / 8) + q;
                s += __hip_atomic_load(&partials[blk * PADB + b],
                                       __ATOMIC_RELAXED,
                                       __HIP_MEMORY_SCOPE_SYSTEM);
            }
            conv[b][c] = s;
        }
    }
    __syncthreads();

    float raw = 0.0f;
    if (tid < NBINS) {
        #pragma unroll
        for (int c = 0; c < 8; ++c) raw += conv[tid][c];
    }
    if (tid < 128) {
        float v = raw;
        #pragma unroll
        for (int o = 32; o > 0; o >>= 1) v += __shfl_down(v, o);
        if ((tid & 63) == 0) ssum[tid >> 6] = v;
    }
    __syncthreads();
    const float S = ssum[0] + ssum[1];

    if (tid < NBINS) {
        const float cnt = raw / S;
        out[tid] = cnt;                                // count
        const float b0 = bins[tid], b1 = bins[tid + 1];
        const float R  = bins[NBINS];                  // R_END = 7.5
        // rdf = cnt / (vol_bin / V) = cnt * R^3 / (b1^3 - b0^3)  (4pi/3 cancels)
        out[201 + tid] = cnt * (R * R * R) / (b1 * b1 * b1 - b0 * b0 * b0);
    }
    if (tid < NBINS + 1) {
        out[100 + tid] = bins[tid];                    // bins passthrough
    }
}

extern "C" void kernel_launch(void* const* d_in, const int* in_sizes, int n_in,
                              void* d_out, int out_size, void* d_ws, size_t ws_size,
                              hipStream_t stream) {
    const float* xyz     = (const float*)d_in[0];
    const float* cell    = (const float*)d_in[1];
    const float* bins    = (const float*)d_in[2];
    const float* offsets = (const float*)d_in[3];
    float* out = (float*)d_out;

    float*    partials = (float*)d_ws;   // NBLOCKS*PADB floats, exch-overwritten
    unsigned* tickets  = (unsigned*)((char*)d_ws +
                                     (size_t)NBLOCKS * PADB * sizeof(float));

    // single graph node: no memset, no second kernel
    rdf_fused<<<NBLOCKS, NTHREADS, 0, stream>>>(xyz, cell, offsets, bins, out,
                                                partials, tickets);
}